// Round 17
// baseline (982.183 us; speedup 1.0000x reference)
//
#include <hip/hip_runtime.h>

typedef unsigned short u16;
typedef __attribute__((ext_vector_type(2))) unsigned short u16x2;
typedef __attribute__((ext_vector_type(8))) short short8;
typedef __attribute__((ext_vector_type(4))) float f32x4;
typedef __attribute__((ext_vector_type(4))) int i32x4;

#define T_CHUNK 128
#define XI_DIRSZ ((size_t)T_CHUNK * 49152)  // elems per (parity,dir) xi buffer

__device__ __forceinline__ u16 f2bf(float f) {
  unsigned u = __float_as_uint(f);
  u += 0x7FFFu + ((u >> 16) & 1u);
  return (u16)(u >> 16);
}
__device__ __forceinline__ float bf2f(u16 v) { return __uint_as_float(((unsigned)v) << 16); }
__device__ __forceinline__ short8 cvt8(const float* __restrict__ p) {
  float4 a = ((const float4*)p)[0];
  float4 b = ((const float4*)p)[1];
  short8 r;
  r[0] = (short)f2bf(a.x); r[1] = (short)f2bf(a.y); r[2] = (short)f2bf(a.z); r[3] = (short)f2bf(a.w);
  r[4] = (short)f2bf(b.x); r[5] = (short)f2bf(b.y); r[6] = (short)f2bf(b.z); r[7] = (short)f2bf(b.w);
  return r;
}

__global__ __launch_bounds__(256) void k_diag(float* o, float v) {
  if (threadIdx.x == 0 && blockIdx.x == 0) o[0] = v;
}

__global__ __launch_bounds__(256) void k_cvt(const float* __restrict__ s, u16* __restrict__ d, int n) {
  int i = blockIdx.x * 256 + threadIdx.x;
  int st = gridDim.x * 256;
  for (; i < n; i += st) d[i] = f2bf(s[i]);
}

// ---- quantize Whh rows to i8 with per-row scale ----
__global__ __launch_bounds__(64) void k_quantw(const float* __restrict__ Wf, const float* __restrict__ Wb,
                                               signed char* __restrict__ Wq, float* __restrict__ rscale) {
  const int row = blockIdx.x;  // [0,1536): dir = row>=768
  const int l = threadIdx.x;
  const float* src = (row < 768) ? (Wf + (size_t)row * 256) : (Wb + (size_t)(row - 768) * 256);
  float4 v = ((const float4*)src)[l];
  float m = fmaxf(fmaxf(fabsf(v.x), fabsf(v.y)), fmaxf(fabsf(v.z), fabsf(v.w)));
#pragma unroll
  for (int off = 32; off; off >>= 1) m = fmaxf(m, __shfl_xor(m, off));
  const float s = 127.f / m;
  char4 q;
  q.x = (signed char)(int)__builtin_rintf(v.x * s);
  q.y = (signed char)(int)__builtin_rintf(v.y * s);
  q.z = (signed char)(int)__builtin_rintf(v.z * s);
  q.w = (signed char)(int)__builtin_rintf(v.w * s);
  ((char4*)(Wq + (size_t)row * 256))[l] = q;
  if (l == 0) rscale[row] = m / (127.f * 127.f);
}

// LDS swizzle (i8 h rows 0..3): 16B-chunk XOR'd by row*5 -> 16 distinct bank-quads per read instr
__device__ __forceinline__ int swz8b(int row, int off) {
  return row * 256 + ((((off >> 4) ^ (row * 5)) & 15) << 4) + (off & 15);
}

// ---- proj body (shared by k_proj0 and k_fused) ----
__device__ __forceinline__ void proj_body(int pid, int cn, const float* __restrict__ x,
                                          const u16* __restrict__ WihB, const float* __restrict__ bihf,
                                          const float* __restrict__ bihb, u16* __restrict__ xi,
                                          u16* Al, u16* Bl) {
  const int tid = threadIdx.x;
  const int l = tid & 63, w = tid >> 6;
  const int lm = l & 15, lq = l >> 4;
  const int dir = pid >= 1536;
  const int q = dir ? pid - 1536 : pid;
  const int r8 = q & 7, rest = q >> 3;
  const int bx = rest % 12;            // n-tile (64 of 768)
  const int by = (rest / 12) * 8 + r8; // t within chunk
  const float* A = x + ((size_t)(dir ? (1024 - (cn + 1) * T_CHUNK) : (cn * T_CHUNK)) + by) * 32768;
  const u16* Bw = WihB + (size_t)dir * 393216;
  const float* bias = dir ? bihb : bihf;
  u16* xo = xi + ((size_t)((cn & 1) * 2 + dir)) * XI_DIRSZ;

  const int n0 = bx << 6;
  const int r0 = tid >> 3, c0 = (tid & 7) << 3;
  const int mt = w >> 1, nh = w & 1;
  f32x4 acc[2] = {};
  for (int k0 = 0; k0 < 512; k0 += 64) {
    __syncthreads();
    *(short8*)&Al[r0 * 72 + c0] = cvt8(A + (size_t)r0 * 512 + k0 + c0);
    *(short8*)&Bl[r0 * 72 + c0] = *(const short8*)(Bw + (size_t)(n0 + r0) * 512 + k0 + c0);
    __syncthreads();
#pragma unroll
    for (int kk = 0; kk < 2; ++kk) {
      short8 af = *(const short8*)&Al[(mt * 16 + lm) * 72 + kk * 32 + lq * 8];
#pragma unroll
      for (int ntp = 0; ntp < 2; ++ntp) {
        short8 bf = *(const short8*)&Bl[((nh * 2 + ntp) * 16 + lm) * 72 + kk * 32 + lq * 8];
        acc[ntp] = __builtin_amdgcn_mfma_f32_16x16x32_bf16(af, bf, acc[ntp], 0, 0, 0);
      }
    }
  }
#pragma unroll
  for (int ntp = 0; ntp < 2; ++ntp) {
    int n = n0 + (nh * 2 + ntp) * 16 + lm;
    float bv = bias[n];
#pragma unroll
    for (int r = 0; r < 4; ++r) {
      int b = mt * 16 + lq * 4 + r;
      xo[(((size_t)by * 8 + (b >> 3)) * 768 + n) * 8 + (b & 7)] = f2bf(acc[ntp][r] + bv);
    }
  }
}

// ---- standalone proj (chunk 0): no LDS cap -> 2 blocks/CU ----
__global__ __launch_bounds__(512, 2) void k_proj0(const float* __restrict__ x, const u16* __restrict__ WihB,
                                                  const float* __restrict__ bihf, const float* __restrict__ bihb,
                                                  u16* __restrict__ xi) {
  __shared__ __align__(16) u16 Al[64 * 72];
  __shared__ __align__(16) u16 Bl[64 * 72];
  proj_body(blockIdx.x, 0, x, WihB, bihf, bihb, xi, Al, Bl);
}

// ============ fused kernel: blocks [0,nscan) = bi-GRU scan chunk; blocks [nscan,..) = proj(chunk+1).
// extern dynamic LDS (64 KB at launch) + 20 KB static = 86 KB -> HW-enforced 1 block/CU:
// scan CUs truly exclusive (no proj co-residency stealing matrix-pipe/VALU issue slots).
__global__ __launch_bounds__(512, 1) void k_fused(
    const float* __restrict__ x, const u16* __restrict__ WihB,
    const float* __restrict__ bihf, const float* __restrict__ bihb,
    u16* __restrict__ xi, const signed char* __restrict__ Wq, const float* __restrict__ rscale,
    const float* __restrict__ bhhf, const float* __restrict__ bhhb,
    float* __restrict__ carry, u16* __restrict__ ob, int chunk, int nscan) {
  extern __shared__ char dynpad[];                    // 64 KB at launch (occupancy limiter)
  __shared__ __align__(16) signed char hb8[2][1024];  // h dbuf i8, swizzled (2 KB)
  __shared__ __align__(16) u16 Al[64 * 72];           // proj staging
  __shared__ __align__(16) u16 Bl[64 * 72];

  const int tid = threadIdx.x;
  const int l = tid & 63, w = tid >> 6;
  const int lm = l & 15, lq = l >> 4;
  if (nscan == -2) {  // never taken at runtime; not provably dead -> dynpad can't be dropped
    dynpad[tid] = (char)chunk;
    __syncthreads();
    ((volatile char*)ob)[tid] = dynpad[(tid * 7) & 65535];
    return;
  }

  if ((int)blockIdx.x >= nscan) {
    proj_body(blockIdx.x - nscan, chunk + 1, x, WihB, bihf, bihb, xi, Al, Bl);
    return;
  }

  // ---------------- scan: 32 blocks = 2 dir x 16 groups of 4 batches; 8 waves x 32-j slices ----------------
  __builtin_amdgcn_s_setprio(1);
  const int dir = blockIdx.x >> 4;
  const int grp = blockIdx.x & 15;
  const int jhL = lq >> 1;
  const int b0 = (lq & 1) << 1;
  const int jL = w * 32 + jhL * 16 + lm;
  const int arow = lm & 3;
  const float* bhh = dir ? bhhb : bhhf;
  const u16* xic = xi + ((size_t)((chunk & 1) * 2 + dir)) * XI_DIRSZ;

  i32x4 bw[6][4];  // all weight fragments in regs
#pragma unroll
  for (int g = 0; g < 3; ++g)
#pragma unroll
    for (int jh = 0; jh < 2; ++jh) {
      const int row = dir * 768 + g * 256 + w * 32 + jh * 16 + lm;
      const signed char* rp = Wq + (size_t)row * 256 + lq * 16;
#pragma unroll
      for (int kk = 0; kk < 4; ++kk) bw[g * 2 + jh][kk] = *(const i32x4*)(rp + kk * 64);
    }
  float rs[3];
#pragma unroll
  for (int g = 0; g < 3; ++g) rs[g] = rscale[dir * 768 + g * 256 + jL];
  const float bR = bhh[jL], bZ = bhh[256 + jL], bN = bhh[512 + jL];

  signed char* hbb = &hb8[0][0];
  float hreg[2];
  if (chunk == 0) {
    hreg[0] = 0.f; hreg[1] = 0.f;
    if (tid < 512) ((unsigned*)hbb)[tid] = 0;
  } else {
#pragma unroll
    for (int i = 0; i < 2; ++i) {
      float v = carry[(size_t)(dir * 64 + grp * 4 + b0 + i) * 256 + jL];
      hreg[i] = v;
      hbb[swz8b(b0 + i, jL)] = (signed char)(int)__builtin_rintf(fminf(fmaxf(v, -1.f), 1.f) * 127.f);
    }
  }

  const int stL0 = dir ? (T_CHUNK - 1) : 0;
  const u16* p_xi = xic + ((size_t)stL0 * 8 + (grp >> 1)) * 6144 + (size_t)jL * 8 + (grp & 1) * 4 + b0;
  const int tg0 = dir ? (1023 - chunk * T_CHUNK) : (chunk * T_CHUNK);
  u16* p_ob = ob + ((size_t)(tg0 * 64 + grp * 4 + b0)) * 512 + dir * 256 + jL;
  const ptrdiff_t dxi = dir ? -49152 : 49152;
  const ptrdiff_t dob = dir ? -32768 : 32768;
  __syncthreads();

  // prefetch step 0's xi (2 batches x 3 gates = 3 dword loads)
  u16x2 xv[3];
#pragma unroll
  for (int g = 0; g < 3; ++g) xv[g] = *(const u16x2*)(p_xi + g * 2048);

  for (int st = 0; st < T_CHUNK; ++st) {
    const int cur = st & 1;
    const signed char* hcur = hbb + cur * 1024;
    // critical-path first: issue all 4 h ds_reads
    i32x4 a4[4];
#pragma unroll
    for (int kk = 0; kk < 4; ++kk) a4[kk] = *(const i32x4*)(hcur + swz8b(arow, kk * 64 + lq * 16));
    // then next step's xi prefetch (hidden under MFMA)
    p_xi += dxi;
    u16x2 xn[3];
    if (st < T_CHUNK - 1) {
#pragma unroll
      for (int g = 0; g < 3; ++g) xn[g] = *(const u16x2*)(p_xi + g * 2048);
    }

    i32x4 acc[2][3] = {};
#pragma unroll
    for (int kk = 0; kk < 4; ++kk)
#pragma unroll
      for (int jh = 0; jh < 2; ++jh)
#pragma unroll
        for (int g = 0; g < 3; ++g)
          acc[jh][g] = __builtin_amdgcn_mfma_i32_16x16x64_i8(a4[kk], bw[g * 2 + jh][kk], acc[jh][g], 0, 0, 0);

    signed char* hnxt = hbb + (cur ^ 1) * 1024;
    i32x4 accS[3];
#pragma unroll
    for (int g = 0; g < 3; ++g) accS[g] = (lq >= 2) ? acc[1][g] : acc[0][g];
#pragma unroll
    for (int i = 0; i < 2; ++i) {
      float fr = (float)((lq & 1) ? accS[0][2 + i] : accS[0][i]) * rs[0];
      float fz = (float)((lq & 1) ? accS[1][2 + i] : accS[1][i]) * rs[1];
      float fn = (float)((lq & 1) ? accS[2][2 + i] : accS[2][i]) * rs[2];
      float ar = bf2f(xv[0][i]) + fr + bR;
      float az = bf2f(xv[1][i]) + fz + bZ;
      float rr = __builtin_amdgcn_rcpf(1.f + __expf(-ar));
      float zz = __builtin_amdgcn_rcpf(1.f + __expf(-az));
      float an = bf2f(xv[2][i]) + rr * (fn + bN);
      float nn = 2.f * __builtin_amdgcn_rcpf(1.f + __expf(-2.f * an)) - 1.f;  // tanh(an)
      float hv = nn + zz * (hreg[i] - nn);
      hreg[i] = hv;
      hnxt[swz8b(b0 + i, jL)] = (signed char)(int)__builtin_rintf(fminf(fmaxf(hv, -1.f), 1.f) * 127.f);
      p_ob[(size_t)i * 512] = f2bf(hv);
    }
#pragma unroll
    for (int g = 0; g < 3; ++g) xv[g] = xn[g];
    p_ob += dob;
    // barrier without vmcnt drain: xi loads / ob stores stay in flight
    asm volatile("s_waitcnt lgkmcnt(0)\n\ts_barrier" ::: "memory");
  }
  __builtin_amdgcn_s_setprio(0);
#pragma unroll
  for (int i = 0; i < 2; ++i)
    carry[(size_t)(dir * 64 + grp * 4 + b0 + i) * 256 + jL] = hreg[i];
}

// ---- segment local features (bf16 in/out) ----
__global__ __launch_bounds__(256) void k_local(const u16* __restrict__ ob, const int* __restrict__ bg,
                                               const int* __restrict__ en, u16* __restrict__ loc) {
  const int b = blockIdx.y, k = blockIdx.x, j = threadIdx.x;
  const int e = en[b * 64 + k], g = bg[b * 64 + k];
  const float ef  = e ? bf2f(ob[(size_t)((e - 1) * 64 + b) * 512 + j]) : 0.f;
  const float bf_ = g ? bf2f(ob[(size_t)((g - 1) * 64 + b) * 512 + j]) : 0.f;
  const float eb  = e ? bf2f(ob[(size_t)((e - 1) * 64 + b) * 512 + 256 + j]) : 0.f;
  const float bb_ = g ? bf2f(ob[(size_t)((g - 1) * 64 + b) * 512 + 256 + j]) : 0.f;
  const size_t o = ((size_t)b * 64 + k) * 512;
  loc[o + j] = f2bf(ef - bf_);
  loc[o + 256 + j] = f2bf(bb_ - eb);
}

__global__ __launch_bounds__(256) void k_sec(const float* __restrict__ ind, int* __restrict__ sec) {
  const int idx = blockIdx.x * 256 + threadIdx.x;  // = s*64 + b
  const int s = idx >> 6, b = idx & 63;
  const float* row = ind + ((size_t)b * 1024 + s) * 64;
  int kk = 0;
  for (int q = 0; q < 64; ++q)
    if (row[q] > 0.5f) kk = q;
  sec[idx] = kk;
}

// ---- MLP GEMM v4: BM=128, BN=128 (A-replication 4x). A direct from global; B (16KB) in
// LDS, balanced XOR swizzle (conflict-free). Register prefetch. XCD window: 8 mb x 4 nh.
__global__ __launch_bounds__(256) void k_gemm_mlp(const u16* __restrict__ obb, const u16* __restrict__ locb,
                                                  const int* __restrict__ sec, const u16* __restrict__ W1b,
                                                  const float* __restrict__ b1, const float* __restrict__ W2,
                                                  float* __restrict__ partial) {
  __shared__ __align__(16) u16 Bl[128][64];  // 16 KB
  const int tid = threadIdx.x;
  const int l = tid & 63, w = tid >> 6;
  const int lm = l & 15, lq = l >> 4;
  // bid = (mb>>3)*32 + nh*8 + (mb&7): same-A blocks share bid%8 (one XCD), window of 32
  const int bid = blockIdx.x;
  const int mb = (bid >> 5) * 8 + (bid & 7);
  const int nh = (bid >> 3) & 3;
  const int m0 = mb << 7, n0 = nh << 7;

  const u16* pa[2];
  const u16* la[2];
#pragma unroll
  for (int mt = 0; mt < 2; ++mt) {
    int mA = m0 + w * 32 + mt * 16 + lm;
    pa[mt] = obb + (size_t)mA * 512;
    la[mt] = locb + ((size_t)(mA & 63) * 64 + sec[mA]) * 512 - 512;
  }
  // B stage: thread t owns W1 row n0+(t>>1), 64B at u16-col (t&1)*32 (4 x 16B chunks)
  const int br = tid >> 1;
  const int bh = tid & 1;
  const u16* wrow = W1b + (size_t)(n0 + br) * 1024 + bh * 32;

  // prologue: k0 = 0 loads
  short8 rb[4];
#pragma unroll
  for (int c = 0; c < 4; ++c) rb[c] = *(const short8*)(wrow + c * 8);
  short8 rA[2][2];
#pragma unroll
  for (int mt = 0; mt < 2; ++mt)
#pragma unroll
    for (int kk = 0; kk < 2; ++kk) rA[mt][kk] = *(const short8*)(pa[mt] + kk * 32 + lq * 8);

  f32x4 acc[2][8] = {};
  for (int k0 = 0; k0 < 1024; k0 += 64) {
    __syncthreads();
#pragma unroll
    for (int c = 0; c < 4; ++c)
      *(short8*)&Bl[br][(((bh * 4 + c) ^ (br & 7)) << 3)] = rb[c];
    __syncthreads();
    short8 aCur[2][2];
#pragma unroll
    for (int mt = 0; mt < 2; ++mt)
#pragma unroll
      for (int kk = 0; kk < 2; ++kk) aCur[mt][kk] = rA[mt][kk];
    if (k0 < 960) {
      const int kn = k0 + 64;
#pragma unroll
      for (int c = 0; c < 4; ++c) rb[c] = *(const short8*)(wrow + kn + c * 8);
#pragma unroll
      for (int mt = 0; mt < 2; ++mt) {
        const u16* base = (kn < 512) ? pa[mt] : la[mt];
#pragma unroll
        for (int kk = 0; kk < 2; ++kk) rA[mt][kk] = *(const short8*)(base + kn + kk * 32 + lq * 8);
      }
    }
#pragma unroll
    for (int kk = 0; kk < 2; ++kk)
#pragma unroll
      for (int nt = 0; nt < 8; ++nt) {
        const int rrow = nt * 16 + lm;
        short8 bf = *(const short8*)&Bl[rrow][(((kk * 4 + lq) ^ (rrow & 7)) << 3)];
#pragma unroll
        for (int mt = 0; mt < 2; ++mt)
          acc[mt][nt] = __builtin_amdgcn_mfma_f32_16x16x32_bf16(aCur[mt][kk], bf, acc[mt][nt], 0, 0, 0);
      }
  }
  // epilogue: fused bias + relu + W2 dot, reduce over n (shfl over lm)
  float s[2][4];
#pragma unroll
  for (int mt = 0; mt < 2; ++mt)
#pragma unroll
    for (int r = 0; r < 4; ++r) s[mt][r] = 0.f;
#pragma unroll
  for (int nt = 0; nt < 8; ++nt) {
    int n = n0 + nt * 16 + lm;
    float bb = b1[n], ww = W2[n];
#pragma unroll
    for (int mt = 0; mt < 2; ++mt)
#pragma unroll
      for (int r = 0; r < 4; ++r) s[mt][r] += fmaxf(acc[mt][nt][r] + bb, 0.f) * ww;
  }
#pragma unroll
  for (int off = 1; off < 16; off <<= 1)
#pragma unroll
    for (int mt = 0; mt < 2; ++mt)
#pragma unroll
      for (int r = 0; r < 4; ++r) s[mt][r] += __shfl_xor(s[mt][r], off);
  if (lm == 0) {
#pragma unroll
    for (int mt = 0; mt < 2; ++mt)
#pragma unroll
      for (int r = 0; r < 4; ++r)
        partial[(size_t)nh * 65536 + m0 + w * 32 + mt * 16 + lq * 4 + r] = s[mt][r];
  }
}

__global__ __launch_bounds__(256) void k_fin2(const float* __restrict__ partial, const float* __restrict__ b2,
                                              float* __restrict__ o) {
  const int i = blockIdx.x * 256 + threadIdx.x;
  float s = b2[0];
#pragma unroll
  for (int q = 0; q < 4; ++q) s += partial[(size_t)q * 65536 + i];
  o[i] = s;
}

extern "C" void kernel_launch(void* const* d_in, const int* in_sizes, int n_in,
                              void* d_out, int out_size, void* d_ws, size_t ws_size,
                              hipStream_t stream) {
  (void)in_sizes; (void)n_in; (void)out_size;
  const float* x    = (const float*)d_in[0];
  const float* sind = (const float*)d_in[2];
  const int*   beg  = (const int*)d_in[3];
  const int*   endi = (const int*)d_in[4];
  const float* Wihf = (const float*)d_in[5];
  const float* Whhf = (const float*)d_in[6];
  const float* bihf = (const float*)d_in[7];
  const float* bhhf = (const float*)d_in[8];
  const float* Wihb = (const float*)d_in[9];
  const float* Whhb = (const float*)d_in[10];
  const float* bihb = (const float*)d_in[11];
  const float* bhhb = (const float*)d_in[12];
  const float* W1   = (const float*)d_in[13];
  const float* b1   = (const float*)d_in[14];
  const float* W2   = (const float*)d_in[15];
  const float* b2   = (const float*)d_in[16];

  const size_t NEED = 124911616ull;
  if (ws_size < NEED) {
    k_diag<<<dim3(1), dim3(256), 0, stream>>>((float*)d_out, 1000.f + (float)(ws_size >> 20));
    return;
  }

  char* ws = (char*)d_ws;
  u16*   xibuf = (u16*)(ws);                    //  50,331,648  [2 parity][2 dir][128][8][768][8] bf16
  u16*   obb   = (u16*)(ws + 50331648);         //  67,108,864  [65536][512] bf16
  u16*   locb  = (u16*)(ws + 117440512);        //   4,194,304  [64][64][512] bf16 (post-scan)
  int*   sec   = (int*)(ws + 121634816);        //     262,144
  float* part  = (float*)(ws + 121896960);      //   1,048,576  [4][65536] f32
  u16*   W1b   = (u16*)(ws + 122945536);        //   1,048,576  [512][1024] bf16
  signed char* Wq = (signed char*)(ws + 123994112);  // 393,216  [2*768][256] i8
  float* rscale = (float*)(ws + 124387328);     //       6,144  [1536]
  float* carry = (float*)(ws + 124780544);      //     131,072  [2][64][256]
  u16*   WihB  = (u16*)(ws + 117440512);        //   1,572,864  [2][768][512] bf16 (pre-k_local, reuses locb)

  k_quantw<<<dim3(1536), dim3(64), 0, stream>>>(Whhf, Whhb, Wq, rscale);
  k_cvt<<<dim3(128), dim3(256), 0, stream>>>(Wihf, WihB, 393216);
  k_cvt<<<dim3(128), dim3(256), 0, stream>>>(Wihb, WihB + 393216, 393216);
  k_cvt<<<dim3(256), dim3(256), 0, stream>>>(W1, W1b, 524288);
  k_sec<<<dim3(256), dim3(256), 0, stream>>>(sind, sec);

  // proj for chunk 0 (standalone, no cap -> 2 blocks/CU)
  k_proj0<<<dim3(3072), dim3(512), 0, stream>>>(x, WihB, bihf, bihb, xibuf);
  // fused scan(c) + proj(c+1); 64 KB dynamic LDS (declared+used) -> 1 block/CU exclusivity
  for (int c = 0; c < 8; ++c)
    k_fused<<<dim3(c < 7 ? 3104 : 32), dim3(512), 65536, stream>>>(x, WihB, bihf, bihb, xibuf, Wq, rscale,
                                                                   bhhf, bhhb, carry, obb, c, 32);

  k_local<<<dim3(64, 64), dim3(256), 0, stream>>>(obb, beg, endi, locb);
  k_gemm_mlp<<<dim3(2048), dim3(256), 0, stream>>>(obb, locb, sec, W1b, b1, W2, part);
  k_fin2<<<dim3(256), dim3(256), 0, stream>>>(part, b2, (float*)d_out);
}

// Round 18
// 976.417 us; speedup vs baseline: 1.0059x; 1.0059x over previous
//
#include <hip/hip_runtime.h>

typedef unsigned short u16;
typedef __attribute__((ext_vector_type(2))) unsigned short u16x2;
typedef __attribute__((ext_vector_type(8))) short short8;
typedef __attribute__((ext_vector_type(4))) float f32x4;
typedef __attribute__((ext_vector_type(4))) int i32x4;

#define T_CHUNK 128
#define XI_DIRSZ ((size_t)T_CHUNK * 49152)  // elems per (parity,dir) xi buffer

__device__ __forceinline__ u16 f2bf(float f) {
  unsigned u = __float_as_uint(f);
  u += 0x7FFFu + ((u >> 16) & 1u);
  return (u16)(u >> 16);
}
__device__ __forceinline__ float bf2f(u16 v) { return __uint_as_float(((unsigned)v) << 16); }
__device__ __forceinline__ short8 cvt8(const float* __restrict__ p) {
  float4 a = ((const float4*)p)[0];
  float4 b = ((const float4*)p)[1];
  short8 r;
  r[0] = (short)f2bf(a.x); r[1] = (short)f2bf(a.y); r[2] = (short)f2bf(a.z); r[3] = (short)f2bf(a.w);
  r[4] = (short)f2bf(b.x); r[5] = (short)f2bf(b.y); r[6] = (short)f2bf(b.z); r[7] = (short)f2bf(b.w);
  return r;
}

__global__ __launch_bounds__(256) void k_diag(float* o, float v) {
  if (threadIdx.x == 0 && blockIdx.x == 0) o[0] = v;
}

__global__ __launch_bounds__(256) void k_cvt(const float* __restrict__ s, u16* __restrict__ d, int n) {
  int i = blockIdx.x * 256 + threadIdx.x;
  int st = gridDim.x * 256;
  for (; i < n; i += st) d[i] = f2bf(s[i]);
}

// ---- quantize Whh rows to i8 with per-row scale ----
__global__ __launch_bounds__(64) void k_quantw(const float* __restrict__ Wf, const float* __restrict__ Wb,
                                               signed char* __restrict__ Wq, float* __restrict__ rscale) {
  const int row = blockIdx.x;  // [0,1536): dir = row>=768
  const int l = threadIdx.x;
  const float* src = (row < 768) ? (Wf + (size_t)row * 256) : (Wb + (size_t)(row - 768) * 256);
  float4 v = ((const float4*)src)[l];
  float m = fmaxf(fmaxf(fabsf(v.x), fabsf(v.y)), fmaxf(fabsf(v.z), fabsf(v.w)));
#pragma unroll
  for (int off = 32; off; off >>= 1) m = fmaxf(m, __shfl_xor(m, off));
  const float s = 127.f / m;
  char4 q;
  q.x = (signed char)(int)__builtin_rintf(v.x * s);
  q.y = (signed char)(int)__builtin_rintf(v.y * s);
  q.z = (signed char)(int)__builtin_rintf(v.z * s);
  q.w = (signed char)(int)__builtin_rintf(v.w * s);
  ((char4*)(Wq + (size_t)row * 256))[l] = q;
  if (l == 0) rscale[row] = m / (127.f * 127.f);
}

// LDS swizzle (i8 h rows 0..3): 16B-chunk XOR'd by row*5 -> 16 distinct bank-quads per read instr
__device__ __forceinline__ int swz8b(int row, int off) {
  return row * 256 + ((((off >> 4) ^ (row * 5)) & 15) << 4) + (off & 15);
}

// ---- proj body (shared by k_proj0 and k_fused) ----
__device__ __forceinline__ void proj_body(int pid, int cn, const float* __restrict__ x,
                                          const u16* __restrict__ WihB, const float* __restrict__ bihf,
                                          const float* __restrict__ bihb, u16* __restrict__ xi,
                                          u16* Al, u16* Bl) {
  const int tid = threadIdx.x;
  const int l = tid & 63, w = tid >> 6;
  const int lm = l & 15, lq = l >> 4;
  const int dir = pid >= 1536;
  const int q = dir ? pid - 1536 : pid;
  const int r8 = q & 7, rest = q >> 3;
  const int bx = rest % 12;            // n-tile (64 of 768)
  const int by = (rest / 12) * 8 + r8; // t within chunk
  const float* A = x + ((size_t)(dir ? (1024 - (cn + 1) * T_CHUNK) : (cn * T_CHUNK)) + by) * 32768;
  const u16* Bw = WihB + (size_t)dir * 393216;
  const float* bias = dir ? bihb : bihf;
  u16* xo = xi + ((size_t)((cn & 1) * 2 + dir)) * XI_DIRSZ;

  const int n0 = bx << 6;
  const int r0 = tid >> 3, c0 = (tid & 7) << 3;
  const int mt = w >> 1, nh = w & 1;
  f32x4 acc[2] = {};
  for (int k0 = 0; k0 < 512; k0 += 64) {
    __syncthreads();
    *(short8*)&Al[r0 * 72 + c0] = cvt8(A + (size_t)r0 * 512 + k0 + c0);
    *(short8*)&Bl[r0 * 72 + c0] = *(const short8*)(Bw + (size_t)(n0 + r0) * 512 + k0 + c0);
    __syncthreads();
#pragma unroll
    for (int kk = 0; kk < 2; ++kk) {
      short8 af = *(const short8*)&Al[(mt * 16 + lm) * 72 + kk * 32 + lq * 8];
#pragma unroll
      for (int ntp = 0; ntp < 2; ++ntp) {
        short8 bf = *(const short8*)&Bl[((nh * 2 + ntp) * 16 + lm) * 72 + kk * 32 + lq * 8];
        acc[ntp] = __builtin_amdgcn_mfma_f32_16x16x32_bf16(af, bf, acc[ntp], 0, 0, 0);
      }
    }
  }
#pragma unroll
  for (int ntp = 0; ntp < 2; ++ntp) {
    int n = n0 + (nh * 2 + ntp) * 16 + lm;
    float bv = bias[n];
#pragma unroll
    for (int r = 0; r < 4; ++r) {
      int b = mt * 16 + lq * 4 + r;
      xo[(((size_t)by * 8 + (b >> 3)) * 768 + n) * 8 + (b & 7)] = f2bf(acc[ntp][r] + bv);
    }
  }
}

// ---- standalone proj (chunk 0): no LDS cap -> 2 blocks/CU ----
__global__ __launch_bounds__(512, 2) void k_proj0(const float* __restrict__ x, const u16* __restrict__ WihB,
                                                  const float* __restrict__ bihf, const float* __restrict__ bihb,
                                                  u16* __restrict__ xi) {
  __shared__ __align__(16) u16 Al[64 * 72];
  __shared__ __align__(16) u16 Bl[64 * 72];
  proj_body(blockIdx.x, 0, x, WihB, bihf, bihb, xi, Al, Bl);
}

// ============ fused kernel: blocks [0,nscan) = bi-GRU scan chunk; blocks [nscan,..) = proj(chunk+1).
// STATIC 64 KB pad whose address ESCAPES into inline asm -> cannot be DCE'd; group segment
// = 86016 B > 80 KB -> HW-enforced 1 block/CU: scan CUs truly exclusive.
__global__ __launch_bounds__(512, 1) void k_fused(
    const float* __restrict__ x, const u16* __restrict__ WihB,
    const float* __restrict__ bihf, const float* __restrict__ bihb,
    u16* __restrict__ xi, const signed char* __restrict__ Wq, const float* __restrict__ rscale,
    const float* __restrict__ bhhf, const float* __restrict__ bhhb,
    float* __restrict__ carry, u16* __restrict__ ob, int chunk, int nscan) {
  __shared__ __align__(16) char bigpad[65536];        // occupancy limiter (address-escaped below)
  __shared__ __align__(16) signed char hb8[2][1024];  // h dbuf i8, swizzled (2 KB)
  __shared__ __align__(16) u16 Al[64 * 72];           // proj staging
  __shared__ __align__(16) u16 Bl[64 * 72];

  const int tid = threadIdx.x;
  const int l = tid & 63, w = tid >> 6;
  const int lm = l & 15, lq = l >> 4;
  // address escape: compiler must allocate bigpad (cannot prove asm doesn't use it)
  {
    unsigned pv = (unsigned)(__UINTPTR_TYPE__)&bigpad[tid];
    asm volatile("" : : "v"(pv));
  }

  if ((int)blockIdx.x >= nscan) {
    proj_body(blockIdx.x - nscan, chunk + 1, x, WihB, bihf, bihb, xi, Al, Bl);
    return;
  }

  // ---------------- scan: 32 blocks = 2 dir x 16 groups of 4 batches; 8 waves x 32-j slices ----------------
  __builtin_amdgcn_s_setprio(1);
  const int dir = blockIdx.x >> 4;
  const int grp = blockIdx.x & 15;
  const int jhL = lq >> 1;
  const int b0 = (lq & 1) << 1;
  const int jL = w * 32 + jhL * 16 + lm;
  const int arow = lm & 3;
  const float* bhh = dir ? bhhb : bhhf;
  const u16* xic = xi + ((size_t)((chunk & 1) * 2 + dir)) * XI_DIRSZ;

  i32x4 bw[6][4];  // all weight fragments in regs
#pragma unroll
  for (int g = 0; g < 3; ++g)
#pragma unroll
    for (int jh = 0; jh < 2; ++jh) {
      const int row = dir * 768 + g * 256 + w * 32 + jh * 16 + lm;
      const signed char* rp = Wq + (size_t)row * 256 + lq * 16;
#pragma unroll
      for (int kk = 0; kk < 4; ++kk) bw[g * 2 + jh][kk] = *(const i32x4*)(rp + kk * 64);
    }
  float rs[3];
#pragma unroll
  for (int g = 0; g < 3; ++g) rs[g] = rscale[dir * 768 + g * 256 + jL];
  const float bR = bhh[jL], bZ = bhh[256 + jL], bN = bhh[512 + jL];

  signed char* hbb = &hb8[0][0];
  float hreg[2];
  if (chunk == 0) {
    hreg[0] = 0.f; hreg[1] = 0.f;
    if (tid < 512) ((unsigned*)hbb)[tid] = 0;
  } else {
#pragma unroll
    for (int i = 0; i < 2; ++i) {
      float v = carry[(size_t)(dir * 64 + grp * 4 + b0 + i) * 256 + jL];
      hreg[i] = v;
      hbb[swz8b(b0 + i, jL)] = (signed char)(int)__builtin_rintf(fminf(fmaxf(v, -1.f), 1.f) * 127.f);
    }
  }

  const int stL0 = dir ? (T_CHUNK - 1) : 0;
  const u16* p_xi = xic + ((size_t)stL0 * 8 + (grp >> 1)) * 6144 + (size_t)jL * 8 + (grp & 1) * 4 + b0;
  const int tg0 = dir ? (1023 - chunk * T_CHUNK) : (chunk * T_CHUNK);
  u16* p_ob = ob + ((size_t)(tg0 * 64 + grp * 4 + b0)) * 512 + dir * 256 + jL;
  const ptrdiff_t dxi = dir ? -49152 : 49152;
  const ptrdiff_t dob = dir ? -32768 : 32768;
  __syncthreads();

  // prefetch step 0's xi (2 batches x 3 gates = 3 dword loads)
  u16x2 xv[3];
#pragma unroll
  for (int g = 0; g < 3; ++g) xv[g] = *(const u16x2*)(p_xi + g * 2048);

  for (int st = 0; st < T_CHUNK; ++st) {
    const int cur = st & 1;
    const signed char* hcur = hbb + cur * 1024;
    // critical-path first: issue all 4 h ds_reads
    i32x4 a4[4];
#pragma unroll
    for (int kk = 0; kk < 4; ++kk) a4[kk] = *(const i32x4*)(hcur + swz8b(arow, kk * 64 + lq * 16));
    // then next step's xi prefetch (hidden under MFMA)
    p_xi += dxi;
    u16x2 xn[3];
    if (st < T_CHUNK - 1) {
#pragma unroll
      for (int g = 0; g < 3; ++g) xn[g] = *(const u16x2*)(p_xi + g * 2048);
    }

    i32x4 acc[2][3] = {};
#pragma unroll
    for (int kk = 0; kk < 4; ++kk)
#pragma unroll
      for (int jh = 0; jh < 2; ++jh)
#pragma unroll
        for (int g = 0; g < 3; ++g)
          acc[jh][g] = __builtin_amdgcn_mfma_i32_16x16x64_i8(a4[kk], bw[g * 2 + jh][kk], acc[jh][g], 0, 0, 0);

    signed char* hnxt = hbb + (cur ^ 1) * 1024;
    i32x4 accS[3];
#pragma unroll
    for (int g = 0; g < 3; ++g) accS[g] = (lq >= 2) ? acc[1][g] : acc[0][g];
#pragma unroll
    for (int i = 0; i < 2; ++i) {
      float fr = (float)((lq & 1) ? accS[0][2 + i] : accS[0][i]) * rs[0];
      float fz = (float)((lq & 1) ? accS[1][2 + i] : accS[1][i]) * rs[1];
      float fn = (float)((lq & 1) ? accS[2][2 + i] : accS[2][i]) * rs[2];
      float ar = bf2f(xv[0][i]) + fr + bR;
      float az = bf2f(xv[1][i]) + fz + bZ;
      float rr = __builtin_amdgcn_rcpf(1.f + __expf(-ar));
      float zz = __builtin_amdgcn_rcpf(1.f + __expf(-az));
      float an = bf2f(xv[2][i]) + rr * (fn + bN);
      float nn = 2.f * __builtin_amdgcn_rcpf(1.f + __expf(-2.f * an)) - 1.f;  // tanh(an)
      float hv = nn + zz * (hreg[i] - nn);
      hreg[i] = hv;
      hnxt[swz8b(b0 + i, jL)] = (signed char)(int)__builtin_rintf(fminf(fmaxf(hv, -1.f), 1.f) * 127.f);
      p_ob[(size_t)i * 512] = f2bf(hv);
    }
#pragma unroll
    for (int g = 0; g < 3; ++g) xv[g] = xn[g];
    p_ob += dob;
    // barrier without vmcnt drain: xi loads / ob stores stay in flight
    asm volatile("s_waitcnt lgkmcnt(0)\n\ts_barrier" ::: "memory");
  }
  __builtin_amdgcn_s_setprio(0);
#pragma unroll
  for (int i = 0; i < 2; ++i)
    carry[(size_t)(dir * 64 + grp * 4 + b0 + i) * 256 + jL] = hreg[i];
}

// ---- segment local features (bf16 in/out) ----
__global__ __launch_bounds__(256) void k_local(const u16* __restrict__ ob, const int* __restrict__ bg,
                                               const int* __restrict__ en, u16* __restrict__ loc) {
  const int b = blockIdx.y, k = blockIdx.x, j = threadIdx.x;
  const int e = en[b * 64 + k], g = bg[b * 64 + k];
  const float ef  = e ? bf2f(ob[(size_t)((e - 1) * 64 + b) * 512 + j]) : 0.f;
  const float bf_ = g ? bf2f(ob[(size_t)((g - 1) * 64 + b) * 512 + j]) : 0.f;
  const float eb  = e ? bf2f(ob[(size_t)((e - 1) * 64 + b) * 512 + 256 + j]) : 0.f;
  const float bb_ = g ? bf2f(ob[(size_t)((g - 1) * 64 + b) * 512 + 256 + j]) : 0.f;
  const size_t o = ((size_t)b * 64 + k) * 512;
  loc[o + j] = f2bf(ef - bf_);
  loc[o + 256 + j] = f2bf(bb_ - eb);
}

__global__ __launch_bounds__(256) void k_sec(const float* __restrict__ ind, int* __restrict__ sec) {
  const int idx = blockIdx.x * 256 + threadIdx.x;  // = s*64 + b
  const int s = idx >> 6, b = idx & 63;
  const float* row = ind + ((size_t)b * 1024 + s) * 64;
  int kk = 0;
  for (int q = 0; q < 64; ++q)
    if (row[q] > 0.5f) kk = q;
  sec[idx] = kk;
}

// ---- MLP GEMM v4: BM=128, BN=128 (A-replication 4x). A direct from global; B (16KB) in
// LDS, balanced XOR swizzle (conflict-free). Register prefetch. XCD window: 8 mb x 4 nh.
__global__ __launch_bounds__(256) void k_gemm_mlp(const u16* __restrict__ obb, const u16* __restrict__ locb,
                                                  const int* __restrict__ sec, const u16* __restrict__ W1b,
                                                  const float* __restrict__ b1, const float* __restrict__ W2,
                                                  float* __restrict__ partial) {
  __shared__ __align__(16) u16 Bl[128][64];  // 16 KB
  const int tid = threadIdx.x;
  const int l = tid & 63, w = tid >> 6;
  const int lm = l & 15, lq = l >> 4;
  // bid = (mb>>3)*32 + nh*8 + (mb&7): same-A blocks share bid%8 (one XCD), window of 32
  const int bid = blockIdx.x;
  const int mb = (bid >> 5) * 8 + (bid & 7);
  const int nh = (bid >> 3) & 3;
  const int m0 = mb << 7, n0 = nh << 7;

  const u16* pa[2];
  const u16* la[2];
#pragma unroll
  for (int mt = 0; mt < 2; ++mt) {
    int mA = m0 + w * 32 + mt * 16 + lm;
    pa[mt] = obb + (size_t)mA * 512;
    la[mt] = locb + ((size_t)(mA & 63) * 64 + sec[mA]) * 512 - 512;
  }
  // B stage: thread t owns W1 row n0+(t>>1), 64B at u16-col (t&1)*32 (4 x 16B chunks)
  const int br = tid >> 1;
  const int bh = tid & 1;
  const u16* wrow = W1b + (size_t)(n0 + br) * 1024 + bh * 32;

  // prologue: k0 = 0 loads
  short8 rb[4];
#pragma unroll
  for (int c = 0; c < 4; ++c) rb[c] = *(const short8*)(wrow + c * 8);
  short8 rA[2][2];
#pragma unroll
  for (int mt = 0; mt < 2; ++mt)
#pragma unroll
    for (int kk = 0; kk < 2; ++kk) rA[mt][kk] = *(const short8*)(pa[mt] + kk * 32 + lq * 8);

  f32x4 acc[2][8] = {};
  for (int k0 = 0; k0 < 1024; k0 += 64) {
    __syncthreads();
#pragma unroll
    for (int c = 0; c < 4; ++c)
      *(short8*)&Bl[br][(((bh * 4 + c) ^ (br & 7)) << 3)] = rb[c];
    __syncthreads();
    short8 aCur[2][2];
#pragma unroll
    for (int mt = 0; mt < 2; ++mt)
#pragma unroll
      for (int kk = 0; kk < 2; ++kk) aCur[mt][kk] = rA[mt][kk];
    if (k0 < 960) {
      const int kn = k0 + 64;
#pragma unroll
      for (int c = 0; c < 4; ++c) rb[c] = *(const short8*)(wrow + kn + c * 8);
#pragma unroll
      for (int mt = 0; mt < 2; ++mt) {
        const u16* base = (kn < 512) ? pa[mt] : la[mt];
#pragma unroll
        for (int kk = 0; kk < 2; ++kk) rA[mt][kk] = *(const short8*)(base + kn + kk * 32 + lq * 8);
      }
    }
#pragma unroll
    for (int kk = 0; kk < 2; ++kk)
#pragma unroll
      for (int nt = 0; nt < 8; ++nt) {
        const int rrow = nt * 16 + lm;
        short8 bf = *(const short8*)&Bl[rrow][(((kk * 4 + lq) ^ (rrow & 7)) << 3)];
#pragma unroll
        for (int mt = 0; mt < 2; ++mt)
          acc[mt][nt] = __builtin_amdgcn_mfma_f32_16x16x32_bf16(aCur[mt][kk], bf, acc[mt][nt], 0, 0, 0);
      }
  }
  // epilogue: fused bias + relu + W2 dot, reduce over n (shfl over lm)
  float s[2][4];
#pragma unroll
  for (int mt = 0; mt < 2; ++mt)
#pragma unroll
    for (int r = 0; r < 4; ++r) s[mt][r] = 0.f;
#pragma unroll
  for (int nt = 0; nt < 8; ++nt) {
    int n = n0 + nt * 16 + lm;
    float bb = b1[n], ww = W2[n];
#pragma unroll
    for (int mt = 0; mt < 2; ++mt)
#pragma unroll
      for (int r = 0; r < 4; ++r) s[mt][r] += fmaxf(acc[mt][nt][r] + bb, 0.f) * ww;
  }
#pragma unroll
  for (int off = 1; off < 16; off <<= 1)
#pragma unroll
    for (int mt = 0; mt < 2; ++mt)
#pragma unroll
      for (int r = 0; r < 4; ++r) s[mt][r] += __shfl_xor(s[mt][r], off);
  if (lm == 0) {
#pragma unroll
    for (int mt = 0; mt < 2; ++mt)
#pragma unroll
      for (int r = 0; r < 4; ++r)
        partial[(size_t)nh * 65536 + m0 + w * 32 + mt * 16 + lq * 4 + r] = s[mt][r];
  }
}

__global__ __launch_bounds__(256) void k_fin2(const float* __restrict__ partial, const float* __restrict__ b2,
                                              float* __restrict__ o) {
  const int i = blockIdx.x * 256 + threadIdx.x;
  float s = b2[0];
#pragma unroll
  for (int q = 0; q < 4; ++q) s += partial[(size_t)q * 65536 + i];
  o[i] = s;
}

extern "C" void kernel_launch(void* const* d_in, const int* in_sizes, int n_in,
                              void* d_out, int out_size, void* d_ws, size_t ws_size,
                              hipStream_t stream) {
  (void)in_sizes; (void)n_in; (void)out_size;
  const float* x    = (const float*)d_in[0];
  const float* sind = (const float*)d_in[2];
  const int*   beg  = (const int*)d_in[3];
  const int*   endi = (const int*)d_in[4];
  const float* Wihf = (const float*)d_in[5];
  const float* Whhf = (const float*)d_in[6];
  const float* bihf = (const float*)d_in[7];
  const float* bhhf = (const float*)d_in[8];
  const float* Wihb = (const float*)d_in[9];
  const float* Whhb = (const float*)d_in[10];
  const float* bihb = (const float*)d_in[11];
  const float* bhhb = (const float*)d_in[12];
  const float* W1   = (const float*)d_in[13];
  const float* b1   = (const float*)d_in[14];
  const float* W2   = (const float*)d_in[15];
  const float* b2   = (const float*)d_in[16];

  const size_t NEED = 124911616ull;
  if (ws_size < NEED) {
    k_diag<<<dim3(1), dim3(256), 0, stream>>>((float*)d_out, 1000.f + (float)(ws_size >> 20));
    return;
  }

  char* ws = (char*)d_ws;
  u16*   xibuf = (u16*)(ws);                    //  50,331,648  [2 parity][2 dir][128][8][768][8] bf16
  u16*   obb   = (u16*)(ws + 50331648);         //  67,108,864  [65536][512] bf16
  u16*   locb  = (u16*)(ws + 117440512);        //   4,194,304  [64][64][512] bf16 (post-scan)
  int*   sec   = (int*)(ws + 121634816);        //     262,144
  float* part  = (float*)(ws + 121896960);      //   1,048,576  [4][65536] f32
  u16*   W1b   = (u16*)(ws + 122945536);        //   1,048,576  [512][1024] bf16
  signed char* Wq = (signed char*)(ws + 123994112);  // 393,216  [2*768][256] i8
  float* rscale = (float*)(ws + 124387328);     //       6,144  [1536]
  float* carry = (float*)(ws + 124780544);      //     131,072  [2][64][256]
  u16*   WihB  = (u16*)(ws + 117440512);        //   1,572,864  [2][768][512] bf16 (pre-k_local, reuses locb)

  k_quantw<<<dim3(1536), dim3(64), 0, stream>>>(Whhf, Whhb, Wq, rscale);
  k_cvt<<<dim3(128), dim3(256), 0, stream>>>(Wihf, WihB, 393216);
  k_cvt<<<dim3(128), dim3(256), 0, stream>>>(Wihb, WihB + 393216, 393216);
  k_cvt<<<dim3(256), dim3(256), 0, stream>>>(W1, W1b, 524288);
  k_sec<<<dim3(256), dim3(256), 0, stream>>>(sind, sec);

  // proj for chunk 0 (standalone, no cap -> 2 blocks/CU)
  k_proj0<<<dim3(3072), dim3(512), 0, stream>>>(x, WihB, bihf, bihb, xibuf);
  // fused scan(c) + proj(c+1); 86 KB static group segment -> 1 block/CU (true exclusivity)
  for (int c = 0; c < 8; ++c)
    k_fused<<<dim3(c < 7 ? 3104 : 32), dim3(512), 0, stream>>>(x, WihB, bihf, bihb, xibuf, Wq, rscale,
                                                               bhhf, bhhb, carry, obb, c, 32);

  k_local<<<dim3(64, 64), dim3(256), 0, stream>>>(obb, beg, endi, locb);
  k_gemm_mlp<<<dim3(2048), dim3(256), 0, stream>>>(obb, locb, sec, W1b, b1, W2, part);
  k_fin2<<<dim3(256), dim3(256), 0, stream>>>(part, b2, (float*)d_out);
}